// Round 7
// baseline (132.723 us; speedup 1.0000x reference)
//
#include <hip/hip_runtime.h>

// ACELoss3D round 7: 8 elements/thread (two float4 z-groups), 6144 one-shot
// blocks. R6's XCD swizzle was neutral -> dropped. Rationale: per-wave MLP
// doubles (20 loads in flight), per-element overhead (addressing, shuffles,
// reduction) halves. All z-halo values still come from adjacent lanes via
// shuffle (lane stride = 16 per z-line; clamps at h&15==0/15 are wave-internal).
// Two-kernel distinct-address reduction kept (R2/R3 atomic contention lesson).

static constexpr int   NTOT   = 6 * 128 * 128 * 128;   // 12,582,912
static constexpr int   NG2    = NTOT / 8;              // 1,572,864 threads
static constexpr int   NBLK2  = NG2 / 256;             // 6144 blocks, exact
static constexpr float ALPHA_ = 0.001f;
static constexpr float MIU_   = 1.0f;
static constexpr float EPS_   = 1e-8f;

__device__ __forceinline__ void wave_reduce3(float& a, float& b, float& c) {
#pragma unroll
  for (int off = 32; off > 0; off >>= 1) {
    a += __shfl_down(a, off);
    b += __shfl_down(b, off);
    c += __shfl_down(c, off);
  }
}

// One output element. di/dj = un-halved first diffs; sx/sy = uxp+uxm, uyp+uym;
// dik/djk/dij = un-halved mixed double-diffs. 2*cik*cjk*cij = 0.25*dik*djk*dij.
__device__ __forceinline__ void elem(
    float uzm, float u0, float uzp,
    float di, float sx, float dj, float sy,
    float dik, float djk, float dij,
    float t, float& s1, float& s2, float& s3) {
  const float dk  = uzp - uzm;
  const float ci2 = 0.25f * di * di;
  const float cj2 = 0.25f * dj * dj;
  const float ck2 = 0.25f * dk * dk;
  const float u2  = u0 + u0;
  const float cii = sx - u2;
  const float cjj = sy - u2;
  const float ckk = (uzp + uzm) - u2;
  const float ss  = ci2 + cj2 + ck2;
  const float ss1 = 1.f + ss;
  const float L = (cii + cjj) + ckk;
  const float M = fmaf(ci2, cii, fmaf(cj2, cjj, ck2 * ckk));
  float curv = fmaf(ss1, L, -M);
  curv = fmaf(-0.25f * dij, dik * djk, curv);
  const float len = __builtin_amdgcn_sqrtf(EPS_ + ss);
  s3 = fmaf(curv * curv, len * __builtin_amdgcn_rcpf(ss1), s3);
  const float tm1 = t - 1.f;
  s1 = fmaf(u0, tm1 * tm1, s1);
  s2 = fmaf(1.f - u0, t * t, s2);
}

__global__ __launch_bounds__(256, 4) void ace_main(
    const float* __restrict__ pred, const float* __restrict__ truth,
    float* __restrict__ partials) {
  const int tid = threadIdx.x;
  const int h = blockIdx.x * 256 + tid;            // 0..NG2-1, exact cover

  const int z8 = (h & 15) << 3;                    // 0,8,...,120
  const int y  = (h >> 4) & 127;
  const int x  = (h >> 11) & 127;
  const size_t base = ((size_t)(h >> 18)) << 21;
  const float* __restrict__ bp = pred + base;

  const int rC  = y << 7;
  const int rYp = ((y < 127) ? y + 1 : 127) << 7;
  const int rYm = ((y > 0)   ? y - 1 : 0)   << 7;
  const int pC  = x << 14;
  const int pXp = ((x < 127) ? x + 1 : 127) << 14;
  const int pXm = ((x > 0)   ? x - 1 : 0)   << 14;

  const float* cC  = bp + pC  + rC  + z8;
  const float* cXP = bp + pXp + rC  + z8;
  const float* cXM = bp + pXm + rC  + z8;
  const float* cYP = bp + pC  + rYp + z8;
  const float* cYM = bp + pC  + rYm + z8;
  const float* cPP = bp + pXp + rYp + z8;
  const float* cMP = bp + pXm + rYp + z8;
  const float* cPM = bp + pXp + rYm + z8;
  const float* cMM = bp + pXm + rYm + z8;
  const float* cT  = truth + base + pC + rC + z8;

  // 20 float4 loads (z8..z8+3 and z8+4..z8+7 for each of 10 columns).
  const float4 vC0 = *(const float4*)(cC);
  const float4 vC1 = *(const float4*)(cC + 4);
  const float4 xP0 = *(const float4*)(cXP);
  const float4 xP1 = *(const float4*)(cXP + 4);
  const float4 xM0 = *(const float4*)(cXM);
  const float4 xM1 = *(const float4*)(cXM + 4);
  const float4 yP0 = *(const float4*)(cYP);
  const float4 yP1 = *(const float4*)(cYP + 4);
  const float4 yM0 = *(const float4*)(cYM);
  const float4 yM1 = *(const float4*)(cYM + 4);
  const float4 pp0 = *(const float4*)(cPP);
  const float4 pp1 = *(const float4*)(cPP + 4);
  const float4 mp0 = *(const float4*)(cMP);
  const float4 mp1 = *(const float4*)(cMP + 4);
  const float4 pm0 = *(const float4*)(cPM);
  const float4 pm1 = *(const float4*)(cPM + 4);
  const float4 mm0 = *(const float4*)(cMM);
  const float4 mm1 = *(const float4*)(cMM + 4);
  const float4 t40 = *(const float4*)(cT);
  const float4 t41 = *(const float4*)(cT + 4);

  // Early combines — xP/xM/yP/yM/corners die here.
  const float dxa = xP0.x - xM0.x, dxb = xP0.y - xM0.y;
  const float dxc = xP0.z - xM0.z, dxd = xP0.w - xM0.w;
  const float dxe = xP1.x - xM1.x, dxf = xP1.y - xM1.y;
  const float dxg = xP1.z - xM1.z, dxh = xP1.w - xM1.w;
  const float sxa = xP0.x + xM0.x, sxb = xP0.y + xM0.y;
  const float sxc = xP0.z + xM0.z, sxd = xP0.w + xM0.w;
  const float sxe = xP1.x + xM1.x, sxf = xP1.y + xM1.y;
  const float sxg = xP1.z + xM1.z, sxh = xP1.w + xM1.w;

  const float dya = yP0.x - yM0.x, dyb = yP0.y - yM0.y;
  const float dyc = yP0.z - yM0.z, dyd = yP0.w - yM0.w;
  const float dye = yP1.x - yM1.x, dyf = yP1.y - yM1.y;
  const float dyg = yP1.z - yM1.z, dyh = yP1.w - yM1.w;
  const float sya = yP0.x + yM0.x, syb = yP0.y + yM0.y;
  const float syc = yP0.z + yM0.z, syd = yP0.w + yM0.w;
  const float sye = yP1.x + yM1.x, syf = yP1.y + yM1.y;
  const float syg = yP1.z + yM1.z, syh = yP1.w + yM1.w;

  const float ja = (pp0.x - mp0.x) - (pm0.x - mm0.x);
  const float jb = (pp0.y - mp0.y) - (pm0.y - mm0.y);
  const float jc = (pp0.z - mp0.z) - (pm0.z - mm0.z);
  const float jd = (pp0.w - mp0.w) - (pm0.w - mm0.w);
  const float je = (pp1.x - mp1.x) - (pm1.x - mm1.x);
  const float jf = (pp1.y - mp1.y) - (pm1.y - mm1.y);
  const float jg = (pp1.z - mp1.z) - (pm1.z - mm1.z);
  const float jh = (pp1.w - mp1.w) - (pm1.w - mm1.w);

  // z-halo from adjacent lanes (lane i-1 holds z8-8..z8-1). Clamp lanes:
  // z8==0 -> (h&15)==0; z8==120 -> (h&15)==15. 16 | 64 so never cross-wave.
  const bool zlo = (z8 == 0), zhi = (z8 == 120);
  float clo  = __shfl_up  (vC1.w, 1);  clo  = zlo ? vC0.x : clo;
  float chi  = __shfl_down(vC0.x, 1);  chi  = zhi ? vC1.w : chi;
  float dxm1 = __shfl_up  (dxh, 1);    dxm1 = zlo ? dxa : dxm1;
  float dxp8 = __shfl_down(dxa, 1);    dxp8 = zhi ? dxh : dxp8;
  float dym1 = __shfl_up  (dyh, 1);    dym1 = zlo ? dya : dym1;
  float dyp8 = __shfl_down(dya, 1);    dyp8 = zhi ? dyh : dyp8;

  float s1 = 0.f, s2 = 0.f, s3 = 0.f;
  elem(clo,   vC0.x, vC0.y, dxa, sxa, dya, sya, dxb - dxm1, dyb - dym1, ja, t40.x, s1, s2, s3);
  elem(vC0.x, vC0.y, vC0.z, dxb, sxb, dyb, syb, dxc - dxa,  dyc - dya,  jb, t40.y, s1, s2, s3);
  elem(vC0.y, vC0.z, vC0.w, dxc, sxc, dyc, syc, dxd - dxb,  dyd - dyb,  jc, t40.z, s1, s2, s3);
  elem(vC0.z, vC0.w, vC1.x, dxd, sxd, dyd, syd, dxe - dxc,  dye - dyc,  jd, t40.w, s1, s2, s3);
  elem(vC0.w, vC1.x, vC1.y, dxe, sxe, dye, sye, dxf - dxd,  dyf - dyd,  je, t41.x, s1, s2, s3);
  elem(vC1.x, vC1.y, vC1.z, dxf, sxf, dyf, syf, dxg - dxe,  dyg - dye,  jf, t41.y, s1, s2, s3);
  elem(vC1.y, vC1.z, vC1.w, dxg, sxg, dyg, syg, dxh - dxf,  dyh - dyf,  jg, t41.z, s1, s2, s3);
  elem(vC1.z, vC1.w, chi,   dxh, sxh, dyh, syh, dxp8 - dxg, dyp8 - dyg, jh, t41.w, s1, s2, s3);

  wave_reduce3(s1, s2, s3);
  __shared__ float l1[4], l2[4], l3[4];
  const int lane = tid & 63, wv = tid >> 6;
  if (lane == 0) { l1[wv] = s1; l2[wv] = s2; l3[wv] = s3; }
  __syncthreads();
  if (tid == 0) {
    partials[blockIdx.x]             = l1[0] + l1[1] + l1[2] + l1[3];
    partials[NBLK2 + blockIdx.x]     = l2[0] + l2[1] + l2[2] + l2[3];
    partials[2 * NBLK2 + blockIdx.x] = l3[0] + l3[1] + l3[2] + l3[3];
  }
}

__global__ __launch_bounds__(1024) void ace_final(
    const float* __restrict__ partials, float* __restrict__ out) {
  const int tid = threadIdx.x;
  float s1 = 0.f, s2 = 0.f, s3 = 0.f;
  const float4* p1 = (const float4*)(partials);
  const float4* p2 = (const float4*)(partials + NBLK2);
  const float4* p3 = (const float4*)(partials + 2 * NBLK2);
  for (int i = tid; i < NBLK2 / 4; i += 1024) {
    const float4 a = p1[i];
    const float4 b = p2[i];
    const float4 c = p3[i];
    s1 += (a.x + a.y) + (a.z + a.w);
    s2 += (b.x + b.y) + (b.z + b.w);
    s3 += (c.x + c.y) + (c.z + c.w);
  }
  wave_reduce3(s1, s2, s3);
  __shared__ float l1[16], l2[16], l3[16];
  const int lane = tid & 63, wv = tid >> 6;
  if (lane == 0) { l1[wv] = s1; l2[wv] = s2; l3[wv] = s3; }
  __syncthreads();
  if (tid == 0) {
    float S1 = 0.f, S2 = 0.f, S3 = 0.f;
#pragma unroll
    for (int w = 0; w < 16; ++w) { S1 += l1[w]; S2 += l2[w]; S3 += l3[w]; }
    out[0] = MIU_ * fabsf(S1) + fabsf(S2) + S3 + ALPHA_ * (float)NTOT;
  }
}

extern "C" void kernel_launch(void* const* d_in, const int* in_sizes, int n_in,
                              void* d_out, int out_size, void* d_ws, size_t ws_size,
                              hipStream_t stream) {
  const float* pred  = (const float*)d_in[0];   // y_pred
  const float* truth = (const float*)d_in[1];   // y_true
  float* out      = (float*)d_out;
  float* partials = (float*)d_ws;               // 3*NBLK2 floats = 73.7 KB

  ace_main<<<NBLK2, 256, 0, stream>>>(pred, truth, partials);
  ace_final<<<1, 1024, 0, stream>>>(partials, out);
}

// Round 8
// 123.753 us; speedup vs baseline: 1.0725x; 1.0725x over previous
//
#include <hip/hip_runtime.h>

// ACELoss3D round 8: R5 structure (best measured: 4 elem/thread, 12288
// one-shot blocks, z-halo via lane shuffles, 15KB L1-resident block working
// set) + forced load batching. R5's VGPR_Count=32 < 40 needed for 10 float4
// loads in flight => compiler serialized loads into ~3 batches, each wave
// paying L1/L2 latency ~3x. sched_barrier(0) after the loads pins all 10
// before any consumer (single waitcnt drain); __launch_bounds__(256,4) lifts
// the VGPR cap to 128 so the destinations can be co-resident.
// R6 XCD swizzle: neutral -> dropped. R7 8-elem: regressed (L1 thrash) -> dropped.

static constexpr int   NTOT   = 6 * 128 * 128 * 128;   // 12,582,912
static constexpr int   NG     = NTOT / 4;              // 3,145,728 groups
static constexpr int   NBLK   = 12288;                 // NBLK*256 == NG exactly
static constexpr float ALPHA_ = 0.001f;
static constexpr float MIU_   = 1.0f;
static constexpr float EPS_   = 1e-8f;

__device__ __forceinline__ void wave_reduce3(float& a, float& b, float& c) {
#pragma unroll
  for (int off = 32; off > 0; off >>= 1) {
    a += __shfl_down(a, off);
    b += __shfl_down(b, off);
    c += __shfl_down(c, off);
  }
}

// One output element. di/dj = un-halved first diffs; sx/sy = uxp+uxm, uyp+uym;
// dik/djk/dij = un-halved mixed double-diffs. 2*cik*cjk*cij = 0.25*dik*djk*dij.
__device__ __forceinline__ void elem(
    float uzm, float u0, float uzp,
    float di, float sx, float dj, float sy,
    float dik, float djk, float dij,
    float t, float& s1, float& s2, float& s3) {
  const float dk  = uzp - uzm;
  const float ci2 = 0.25f * di * di;
  const float cj2 = 0.25f * dj * dj;
  const float ck2 = 0.25f * dk * dk;
  const float u2  = u0 + u0;
  const float cii = sx - u2;
  const float cjj = sy - u2;
  const float ckk = (uzp + uzm) - u2;
  const float ss  = ci2 + cj2 + ck2;
  const float ss1 = 1.f + ss;
  const float L = (cii + cjj) + ckk;
  const float M = fmaf(ci2, cii, fmaf(cj2, cjj, ck2 * ckk));
  float curv = fmaf(ss1, L, -M);
  curv = fmaf(-0.25f * dij, dik * djk, curv);
  const float len = __builtin_amdgcn_sqrtf(EPS_ + ss);
  s3 = fmaf(curv * curv, len * __builtin_amdgcn_rcpf(ss1), s3);
  const float tm1 = t - 1.f;
  s1 = fmaf(u0, tm1 * tm1, s1);
  s2 = fmaf(1.f - u0, t * t, s2);
}

__global__ __launch_bounds__(256, 4) void ace_main(
    const float* __restrict__ pred, const float* __restrict__ truth,
    float* __restrict__ partials) {
  const int tid = threadIdx.x;
  const int g = blockIdx.x * 256 + tid;            // 0..NG-1, exact cover

  const int z0 = (g & 31) << 2;                    // 0,4,...,124
  const int y  = (g >> 5) & 127;
  const int x  = (g >> 12) & 127;
  const size_t base = ((size_t)(g >> 19)) << 21;
  const float* __restrict__ bp = pred + base;

  const int rC  = y << 7;
  const int rYp = ((y < 127) ? y + 1 : 127) << 7;
  const int rYm = ((y > 0)   ? y - 1 : 0)   << 7;
  const int pC  = x << 14;
  const int pXp = ((x < 127) ? x + 1 : 127) << 14;
  const int pXm = ((x > 0)   ? x - 1 : 0)   << 14;

  // 10 float4 loads — all pinned in flight before any consumer.
  const float4 vC  = *(const float4*)(bp + pC  + rC  + z0);
  const float4 vXP = *(const float4*)(bp + pXp + rC  + z0);
  const float4 vXM = *(const float4*)(bp + pXm + rC  + z0);
  const float4 vYP = *(const float4*)(bp + pC  + rYp + z0);
  const float4 vYM = *(const float4*)(bp + pC  + rYm + z0);
  const float4 vPP = *(const float4*)(bp + pXp + rYp + z0);
  const float4 vMP = *(const float4*)(bp + pXm + rYp + z0);
  const float4 vPM = *(const float4*)(bp + pXp + rYm + z0);
  const float4 vMM = *(const float4*)(bp + pXm + rYm + z0);
  const float4 t4  = *(const float4*)(truth + base + pC + rC + z0);
#if defined(__has_builtin)
#if __has_builtin(__builtin_amdgcn_sched_barrier)
  __builtin_amdgcn_sched_barrier(0);   // keep all 10 loads issued before math
#endif
#endif

  // Early combines.
  const float dxa = vXP.x - vXM.x, dxb = vXP.y - vXM.y;
  const float dxc = vXP.z - vXM.z, dxd = vXP.w - vXM.w;
  const float sxa = vXP.x + vXM.x, sxb = vXP.y + vXM.y;
  const float sxc = vXP.z + vXM.z, sxd = vXP.w + vXM.w;
  const float dya = vYP.x - vYM.x, dyb = vYP.y - vYM.y;
  const float dyc = vYP.z - vYM.z, dyd = vYP.w - vYM.w;
  const float sya = vYP.x + vYM.x, syb = vYP.y + vYM.y;
  const float syc = vYP.z + vYM.z, syd = vYP.w + vYM.w;
  const float ja = (vPP.x - vMP.x) - (vPM.x - vMM.x);
  const float jb = (vPP.y - vMP.y) - (vPM.y - vMM.y);
  const float jc = (vPP.z - vMP.z) - (vPM.z - vMM.z);
  const float jd = (vPP.w - vMP.w) - (vPM.w - vMM.w);

  // z-boundary values from adjacent lanes (lane i-1 holds z0-4..z0-1).
  // Clamp lanes: z0==0 (lanes 0,32) -> own .x; z0==124 (lanes 31,63) -> own .w.
  const bool zlo = (z0 == 0), zhi = (z0 == 124);
  float clo  = __shfl_up  (vC.w, 1);  clo  = zlo ? vC.x : clo;
  float chi  = __shfl_down(vC.x, 1);  chi  = zhi ? vC.w : chi;
  float dxm1 = __shfl_up  (dxd, 1);   dxm1 = zlo ? dxa : dxm1;
  float dxp4 = __shfl_down(dxa, 1);   dxp4 = zhi ? dxd : dxp4;
  float dym1 = __shfl_up  (dyd, 1);   dym1 = zlo ? dya : dym1;
  float dyp4 = __shfl_down(dya, 1);   dyp4 = zhi ? dyd : dyp4;

  float s1 = 0.f, s2 = 0.f, s3 = 0.f;
  elem(clo,  vC.x, vC.y, dxa, sxa, dya, sya, dxb - dxm1, dyb - dym1, ja, t4.x, s1, s2, s3);
  elem(vC.x, vC.y, vC.z, dxb, sxb, dyb, syb, dxc - dxa,  dyc - dya,  jb, t4.y, s1, s2, s3);
  elem(vC.y, vC.z, vC.w, dxc, sxc, dyc, syc, dxd - dxb,  dyd - dyb,  jc, t4.z, s1, s2, s3);
  elem(vC.z, vC.w, chi,  dxd, sxd, dyd, syd, dxp4 - dxc, dyp4 - dyc, jd, t4.w, s1, s2, s3);

  wave_reduce3(s1, s2, s3);
  __shared__ float l1[4], l2[4], l3[4];
  const int lane = tid & 63, wv = tid >> 6;
  if (lane == 0) { l1[wv] = s1; l2[wv] = s2; l3[wv] = s3; }
  __syncthreads();
  if (tid == 0) {
    partials[blockIdx.x]            = l1[0] + l1[1] + l1[2] + l1[3];
    partials[NBLK + blockIdx.x]     = l2[0] + l2[1] + l2[2] + l2[3];
    partials[2 * NBLK + blockIdx.x] = l3[0] + l3[1] + l3[2] + l3[3];
  }
}

__global__ __launch_bounds__(1024) void ace_final(
    const float* __restrict__ partials, float* __restrict__ out) {
  const int tid = threadIdx.x;
  float s1 = 0.f, s2 = 0.f, s3 = 0.f;
  const float4* p1 = (const float4*)(partials);
  const float4* p2 = (const float4*)(partials + NBLK);
  const float4* p3 = (const float4*)(partials + 2 * NBLK);
#pragma unroll
  for (int i = 0; i < NBLK / 4 / 1024; ++i) {
    const float4 a = p1[i * 1024 + tid];
    const float4 b = p2[i * 1024 + tid];
    const float4 c = p3[i * 1024 + tid];
    s1 += (a.x + a.y) + (a.z + a.w);
    s2 += (b.x + b.y) + (b.z + b.w);
    s3 += (c.x + c.y) + (c.z + c.w);
  }
  wave_reduce3(s1, s2, s3);
  __shared__ float l1[16], l2[16], l3[16];
  const int lane = tid & 63, wv = tid >> 6;
  if (lane == 0) { l1[wv] = s1; l2[wv] = s2; l3[wv] = s3; }
  __syncthreads();
  if (tid == 0) {
    float S1 = 0.f, S2 = 0.f, S3 = 0.f;
#pragma unroll
    for (int w = 0; w < 16; ++w) { S1 += l1[w]; S2 += l2[w]; S3 += l3[w]; }
    out[0] = MIU_ * fabsf(S1) + fabsf(S2) + S3 + ALPHA_ * (float)NTOT;
  }
}

extern "C" void kernel_launch(void* const* d_in, const int* in_sizes, int n_in,
                              void* d_out, int out_size, void* d_ws, size_t ws_size,
                              hipStream_t stream) {
  const float* pred  = (const float*)d_in[0];   // y_pred
  const float* truth = (const float*)d_in[1];   // y_true
  float* out      = (float*)d_out;
  float* partials = (float*)d_ws;               // 3*NBLK floats = 147 KB

  ace_main<<<NBLK, 256, 0, stream>>>(pred, truth, partials);
  ace_final<<<1, 1024, 0, stream>>>(partials, out);
}

// Round 9
// 120.208 us; speedup vs baseline: 1.1041x; 1.0295x over previous
//
#include <hip/hip_runtime.h>

// ACELoss3D round 9: 4x4x128 block tile (512 threads, 4 elem/thread).
// R5/R8's 1x8x128 slab loads 30 pred rows per 8 output rows (3.75x L1/L2
// amplification, ~238MB L2->L1). A 4x4 xy-tile loads 36 rows per 16 output
// rows (2.25x, ~160MB), working set 26KB < 32KB L1. Loads/thread, VALU work,
// shuffle z-halo, sched_barrier load batching, and the two-kernel
// distinct-address reduction are all unchanged from R8.
// History: R6 XCD swizzle neutral; R7 8-elem regressed (L1 thrash + load
// serialization); R8 sched_barrier +1.5us.

static constexpr int   NTOT   = 6 * 128 * 128 * 128;   // 12,582,912
static constexpr int   NBLK   = 6144;                  // 32x32 xy-tiles * 6 bc
static constexpr float ALPHA_ = 0.001f;
static constexpr float MIU_   = 1.0f;
static constexpr float EPS_   = 1e-8f;

__device__ __forceinline__ void wave_reduce3(float& a, float& b, float& c) {
#pragma unroll
  for (int off = 32; off > 0; off >>= 1) {
    a += __shfl_down(a, off);
    b += __shfl_down(b, off);
    c += __shfl_down(c, off);
  }
}

// One output element. di/dj = un-halved first diffs; sx/sy = uxp+uxm, uyp+uym;
// dik/djk/dij = un-halved mixed double-diffs. 2*cik*cjk*cij = 0.25*dik*djk*dij.
__device__ __forceinline__ void elem(
    float uzm, float u0, float uzp,
    float di, float sx, float dj, float sy,
    float dik, float djk, float dij,
    float t, float& s1, float& s2, float& s3) {
  const float dk  = uzp - uzm;
  const float ci2 = 0.25f * di * di;
  const float cj2 = 0.25f * dj * dj;
  const float ck2 = 0.25f * dk * dk;
  const float u2  = u0 + u0;
  const float cii = sx - u2;
  const float cjj = sy - u2;
  const float ckk = (uzp + uzm) - u2;
  const float ss  = ci2 + cj2 + ck2;
  const float ss1 = 1.f + ss;
  const float L = (cii + cjj) + ckk;
  const float M = fmaf(ci2, cii, fmaf(cj2, cjj, ck2 * ckk));
  float curv = fmaf(ss1, L, -M);
  curv = fmaf(-0.25f * dij, dik * djk, curv);
  const float len = __builtin_amdgcn_sqrtf(EPS_ + ss);
  s3 = fmaf(curv * curv, len * __builtin_amdgcn_rcpf(ss1), s3);
  const float tm1 = t - 1.f;
  s1 = fmaf(u0, tm1 * tm1, s1);
  s2 = fmaf(1.f - u0, t * t, s2);
}

__global__ __launch_bounds__(512, 4) void ace_main(
    const float* __restrict__ pred, const float* __restrict__ truth,
    float* __restrict__ partials) {
  const int tid = threadIdx.x;
  // Block -> (bc, y-tile, x-tile); thread -> (x in 0..3, y in 0..3, z-group).
  const int rem = blockIdx.x & 1023;        // 32x32 xy tiles
  const int bc  = blockIdx.x >> 10;         // 0..5
  const int x   = ((rem & 31) << 2)  + (tid >> 7);         // x-tile fastest
  const int y   = ((rem >> 5) << 2)  + ((tid >> 5) & 3);
  const int z0  = (tid & 31) << 2;                         // 0,4,...,124
  const size_t base = ((size_t)bc) << 21;
  const float* __restrict__ bp = pred + base;

  const int rC  = y << 7;
  const int rYp = ((y < 127) ? y + 1 : 127) << 7;
  const int rYm = ((y > 0)   ? y - 1 : 0)   << 7;
  const int pC  = x << 14;
  const int pXp = ((x < 127) ? x + 1 : 127) << 14;
  const int pXm = ((x > 0)   ? x - 1 : 0)   << 14;

  // 10 float4 loads — all pinned in flight before any consumer.
  const float4 vC  = *(const float4*)(bp + pC  + rC  + z0);
  const float4 vXP = *(const float4*)(bp + pXp + rC  + z0);
  const float4 vXM = *(const float4*)(bp + pXm + rC  + z0);
  const float4 vYP = *(const float4*)(bp + pC  + rYp + z0);
  const float4 vYM = *(const float4*)(bp + pC  + rYm + z0);
  const float4 vPP = *(const float4*)(bp + pXp + rYp + z0);
  const float4 vMP = *(const float4*)(bp + pXm + rYp + z0);
  const float4 vPM = *(const float4*)(bp + pXp + rYm + z0);
  const float4 vMM = *(const float4*)(bp + pXm + rYm + z0);
  const float4 t4  = *(const float4*)(truth + base + pC + rC + z0);
#if defined(__has_builtin)
#if __has_builtin(__builtin_amdgcn_sched_barrier)
  __builtin_amdgcn_sched_barrier(0);   // keep all 10 loads issued before math
#endif
#endif

  // Early combines.
  const float dxa = vXP.x - vXM.x, dxb = vXP.y - vXM.y;
  const float dxc = vXP.z - vXM.z, dxd = vXP.w - vXM.w;
  const float sxa = vXP.x + vXM.x, sxb = vXP.y + vXM.y;
  const float sxc = vXP.z + vXM.z, sxd = vXP.w + vXM.w;
  const float dya = vYP.x - vYM.x, dyb = vYP.y - vYM.y;
  const float dyc = vYP.z - vYM.z, dyd = vYP.w - vYM.w;
  const float sya = vYP.x + vYM.x, syb = vYP.y + vYM.y;
  const float syc = vYP.z + vYM.z, syd = vYP.w + vYM.w;
  const float ja = (vPP.x - vMP.x) - (vPM.x - vMM.x);
  const float jb = (vPP.y - vMP.y) - (vPM.y - vMM.y);
  const float jc = (vPP.z - vMP.z) - (vPM.z - vMM.z);
  const float jd = (vPP.w - vMP.w) - (vPM.w - vMM.w);

  // z-halo from adjacent lanes (lane i-1 holds z0-4..z0-1). z runs over 32
  // consecutive lanes; clamp lanes (tid&31)==0 / ==31 are select-overridden,
  // so the +-1 shuffles never leak across the 32-lane z-line boundary.
  const bool zlo = (z0 == 0), zhi = (z0 == 124);
  float clo  = __shfl_up  (vC.w, 1);  clo  = zlo ? vC.x : clo;
  float chi  = __shfl_down(vC.x, 1);  chi  = zhi ? vC.w : chi;
  float dxm1 = __shfl_up  (dxd, 1);   dxm1 = zlo ? dxa : dxm1;
  float dxp4 = __shfl_down(dxa, 1);   dxp4 = zhi ? dxd : dxp4;
  float dym1 = __shfl_up  (dyd, 1);   dym1 = zlo ? dya : dym1;
  float dyp4 = __shfl_down(dya, 1);   dyp4 = zhi ? dyd : dyp4;

  float s1 = 0.f, s2 = 0.f, s3 = 0.f;
  elem(clo,  vC.x, vC.y, dxa, sxa, dya, sya, dxb - dxm1, dyb - dym1, ja, t4.x, s1, s2, s3);
  elem(vC.x, vC.y, vC.z, dxb, sxb, dyb, syb, dxc - dxa,  dyc - dya,  jb, t4.y, s1, s2, s3);
  elem(vC.y, vC.z, vC.w, dxc, sxc, dyc, syc, dxd - dxb,  dyd - dyb,  jc, t4.z, s1, s2, s3);
  elem(vC.z, vC.w, chi,  dxd, sxd, dyd, syd, dxp4 - dxc, dyp4 - dyc, jd, t4.w, s1, s2, s3);

  wave_reduce3(s1, s2, s3);
  __shared__ float l1[8], l2[8], l3[8];
  const int lane = tid & 63, wv = tid >> 6;
  if (lane == 0) { l1[wv] = s1; l2[wv] = s2; l3[wv] = s3; }
  __syncthreads();
  if (tid == 0) {
    float p1 = 0.f, p2 = 0.f, p3 = 0.f;
#pragma unroll
    for (int w = 0; w < 8; ++w) { p1 += l1[w]; p2 += l2[w]; p3 += l3[w]; }
    partials[blockIdx.x]            = p1;
    partials[NBLK + blockIdx.x]     = p2;
    partials[2 * NBLK + blockIdx.x] = p3;
  }
}

__global__ __launch_bounds__(1024) void ace_final(
    const float* __restrict__ partials, float* __restrict__ out) {
  const int tid = threadIdx.x;
  float s1 = 0.f, s2 = 0.f, s3 = 0.f;
  const float4* p1 = (const float4*)(partials);
  const float4* p2 = (const float4*)(partials + NBLK);
  const float4* p3 = (const float4*)(partials + 2 * NBLK);
  for (int i = tid; i < NBLK / 4; i += 1024) {
    const float4 a = p1[i];
    const float4 b = p2[i];
    const float4 c = p3[i];
    s1 += (a.x + a.y) + (a.z + a.w);
    s2 += (b.x + b.y) + (b.z + b.w);
    s3 += (c.x + c.y) + (c.z + c.w);
  }
  wave_reduce3(s1, s2, s3);
  __shared__ float l1[16], l2[16], l3[16];
  const int lane = tid & 63, wv = tid >> 6;
  if (lane == 0) { l1[wv] = s1; l2[wv] = s2; l3[wv] = s3; }
  __syncthreads();
  if (tid == 0) {
    float S1 = 0.f, S2 = 0.f, S3 = 0.f;
#pragma unroll
    for (int w = 0; w < 16; ++w) { S1 += l1[w]; S2 += l2[w]; S3 += l3[w]; }
    out[0] = MIU_ * fabsf(S1) + fabsf(S2) + S3 + ALPHA_ * (float)NTOT;
  }
}

extern "C" void kernel_launch(void* const* d_in, const int* in_sizes, int n_in,
                              void* d_out, int out_size, void* d_ws, size_t ws_size,
                              hipStream_t stream) {
  const float* pred  = (const float*)d_in[0];   // y_pred
  const float* truth = (const float*)d_in[1];   // y_true
  float* out      = (float*)d_out;
  float* partials = (float*)d_ws;               // 3*NBLK floats = 73.7 KB

  ace_main<<<NBLK, 512, 0, stream>>>(pred, truth, partials);
  ace_final<<<1, 1024, 0, stream>>>(partials, out);
}

// Round 10
// 118.283 us; speedup vs baseline: 1.1221x; 1.0163x over previous
//
#include <hip/hip_runtime.h>

// ACELoss3D round 10: R9 (4x4x128 tile, 512 thr) + wave-internal y-exchange.
// Within a wave, lanes 0-31 / 32-63 hold adjacent y rows (even/odd y-sub), so
// the INWARD y-neighbor (center row + its x-diff) comes from __shfl_xor(.,32);
// only the OUTWARD y row (y-1 lower half, y+1 upper half) is loaded. VMEM
// drops 10->7 float4/thread (-30% L1 issue+return); +8 bpermutes on the idle
// DS pipe. dy/dij get a +-1 sign per half; inward row is never clamped.
// History: R6 XCD swizzle neutral; R7 8-elem regressed; R8 sched_barrier
// +1.5us; R9 4x4 tile +3.5us.

static constexpr int   NTOT   = 6 * 128 * 128 * 128;   // 12,582,912
static constexpr int   NBLK   = 6144;                  // 32x32 xy-tiles * 6 bc
static constexpr float ALPHA_ = 0.001f;
static constexpr float MIU_   = 1.0f;
static constexpr float EPS_   = 1e-8f;

__device__ __forceinline__ void wave_reduce3(float& a, float& b, float& c) {
#pragma unroll
  for (int off = 32; off > 0; off >>= 1) {
    a += __shfl_down(a, off);
    b += __shfl_down(b, off);
    c += __shfl_down(c, off);
  }
}

// One output element. di/dj = un-halved first diffs; sx/sy = uxp+uxm, uyp+uym;
// dik/djk/dij = un-halved mixed double-diffs. 2*cik*cjk*cij = 0.25*dik*djk*dij.
__device__ __forceinline__ void elem(
    float uzm, float u0, float uzp,
    float di, float sx, float dj, float sy,
    float dik, float djk, float dij,
    float t, float& s1, float& s2, float& s3) {
  const float dk  = uzp - uzm;
  const float ci2 = 0.25f * di * di;
  const float cj2 = 0.25f * dj * dj;
  const float ck2 = 0.25f * dk * dk;
  const float u2  = u0 + u0;
  const float cii = sx - u2;
  const float cjj = sy - u2;
  const float ckk = (uzp + uzm) - u2;
  const float ss  = ci2 + cj2 + ck2;
  const float ss1 = 1.f + ss;
  const float L = (cii + cjj) + ckk;
  const float M = fmaf(ci2, cii, fmaf(cj2, cjj, ck2 * ckk));
  float curv = fmaf(ss1, L, -M);
  curv = fmaf(-0.25f * dij, dik * djk, curv);
  const float len = __builtin_amdgcn_sqrtf(EPS_ + ss);
  s3 = fmaf(curv * curv, len * __builtin_amdgcn_rcpf(ss1), s3);
  const float tm1 = t - 1.f;
  s1 = fmaf(u0, tm1 * tm1, s1);
  s2 = fmaf(1.f - u0, t * t, s2);
}

__global__ __launch_bounds__(512, 4) void ace_main(
    const float* __restrict__ pred, const float* __restrict__ truth,
    float* __restrict__ partials) {
  const int tid = threadIdx.x;
  // Block -> (bc, y-tile, x-tile); thread -> (x-sub, y-sub, z-group).
  const int rem = blockIdx.x & 1023;        // 32x32 xy tiles
  const int bc  = blockIdx.x >> 10;         // 0..5
  const int x   = ((rem & 31) << 2)  + (tid >> 7);
  const int y   = ((rem >> 5) << 2)  + ((tid >> 5) & 3);
  const int z0  = (tid & 31) << 2;                         // 0,4,...,124
  const size_t base = ((size_t)bc) << 21;
  const float* __restrict__ bp = pred + base;

  // Wave halves: lanes 0-31 = even y-sub, lanes 32-63 = odd y-sub (adjacent y).
  const bool upper = (tid & 32) != 0;
  const float sgn  = upper ? 1.f : -1.f;
  const int yOut = upper ? ((y < 127) ? y + 1 : 127) : ((y > 0) ? y - 1 : 0);
  const int rO  = yOut << 7;
  const int rC  = y << 7;
  const int pC  = x << 14;
  const int pXp = ((x < 127) ? x + 1 : 127) << 14;
  const int pXm = ((x > 0)   ? x - 1 : 0)   << 14;

  // 7 float4 loads (was 10) — all pinned in flight before any consumer.
  const float4 vC  = *(const float4*)(bp + pC  + rC + z0);
  const float4 vXP = *(const float4*)(bp + pXp + rC + z0);
  const float4 vXM = *(const float4*)(bp + pXm + rC + z0);
  const float4 vOY = *(const float4*)(bp + pC  + rO + z0);   // outward y row
  const float4 vOP = *(const float4*)(bp + pXp + rO + z0);
  const float4 vOM = *(const float4*)(bp + pXm + rO + z0);
  const float4 t4  = *(const float4*)(truth + base + pC + rC + z0);
#if defined(__has_builtin)
#if __has_builtin(__builtin_amdgcn_sched_barrier)
  __builtin_amdgcn_sched_barrier(0);   // keep all 7 loads issued before math
#endif
#endif

  // Center-row x combines.
  const float dxa = vXP.x - vXM.x, dxb = vXP.y - vXM.y;
  const float dxc = vXP.z - vXM.z, dxd = vXP.w - vXM.w;
  const float sxa = vXP.x + vXM.x, sxb = vXP.y + vXM.y;
  const float sxc = vXP.z + vXM.z, sxd = vXP.w + vXM.w;
  // Outward-row x-diff.
  const float dOa = vOP.x - vOM.x, dOb = vOP.y - vOM.y;
  const float dOc = vOP.z - vOM.z, dOd = vOP.w - vOM.w;

  // Inward y-neighbor via half-wave exchange (partner row is never clamped).
  const float iCa = __shfl_xor(vC.x, 32), iCb = __shfl_xor(vC.y, 32);
  const float iCc = __shfl_xor(vC.z, 32), iCd = __shfl_xor(vC.w, 32);
  const float iDa = __shfl_xor(dxa, 32),  iDb = __shfl_xor(dxb, 32);
  const float iDc = __shfl_xor(dxc, 32),  iDd = __shfl_xor(dxd, 32);

  // y combines: sy order-free; dy/j get the half sign.
  const float sya = iCa + vOY.x, syb = iCb + vOY.y;
  const float syc = iCc + vOY.z, syd = iCd + vOY.w;
  const float dya = sgn * (vOY.x - iCa), dyb = sgn * (vOY.y - iCb);
  const float dyc = sgn * (vOY.z - iCc), dyd = sgn * (vOY.w - iCd);
  const float ja  = sgn * (dOa - iDa),   jb  = sgn * (dOb - iDb);
  const float jc  = sgn * (dOc - iDc),   jd  = sgn * (dOd - iDd);

  // z-halo from adjacent lanes (lane i-1 holds z0-4..z0-1). Clamp lanes
  // (tid&31)==0 / ==31 are select-overridden, so the +-1 shuffles never leak
  // across the 32-lane z-line boundary (where y changes).
  const bool zlo = (z0 == 0), zhi = (z0 == 124);
  float clo  = __shfl_up  (vC.w, 1);  clo  = zlo ? vC.x : clo;
  float chi  = __shfl_down(vC.x, 1);  chi  = zhi ? vC.w : chi;
  float dxm1 = __shfl_up  (dxd, 1);   dxm1 = zlo ? dxa : dxm1;
  float dxp4 = __shfl_down(dxa, 1);   dxp4 = zhi ? dxd : dxp4;
  float dym1 = __shfl_up  (dyd, 1);   dym1 = zlo ? dya : dym1;
  float dyp4 = __shfl_down(dya, 1);   dyp4 = zhi ? dyd : dyp4;

  float s1 = 0.f, s2 = 0.f, s3 = 0.f;
  elem(clo,  vC.x, vC.y, dxa, sxa, dya, sya, dxb - dxm1, dyb - dym1, ja, t4.x, s1, s2, s3);
  elem(vC.x, vC.y, vC.z, dxb, sxb, dyb, syb, dxc - dxa,  dyc - dya,  jb, t4.y, s1, s2, s3);
  elem(vC.y, vC.z, vC.w, dxc, sxc, dyc, syc, dxd - dxb,  dyd - dyb,  jc, t4.z, s1, s2, s3);
  elem(vC.z, vC.w, chi,  dxd, sxd, dyd, syd, dxp4 - dxc, dyp4 - dyc, jd, t4.w, s1, s2, s3);

  wave_reduce3(s1, s2, s3);
  __shared__ float l1[8], l2[8], l3[8];
  const int lane = tid & 63, wv = tid >> 6;
  if (lane == 0) { l1[wv] = s1; l2[wv] = s2; l3[wv] = s3; }
  __syncthreads();
  if (tid == 0) {
    float p1 = 0.f, p2 = 0.f, p3 = 0.f;
#pragma unroll
    for (int w = 0; w < 8; ++w) { p1 += l1[w]; p2 += l2[w]; p3 += l3[w]; }
    partials[blockIdx.x]            = p1;
    partials[NBLK + blockIdx.x]     = p2;
    partials[2 * NBLK + blockIdx.x] = p3;
  }
}

__global__ __launch_bounds__(1024) void ace_final(
    const float* __restrict__ partials, float* __restrict__ out) {
  const int tid = threadIdx.x;
  float s1 = 0.f, s2 = 0.f, s3 = 0.f;
  const float4* p1 = (const float4*)(partials);
  const float4* p2 = (const float4*)(partials + NBLK);
  const float4* p3 = (const float4*)(partials + 2 * NBLK);
  for (int i = tid; i < NBLK / 4; i += 1024) {
    const float4 a = p1[i];
    const float4 b = p2[i];
    const float4 c = p3[i];
    s1 += (a.x + a.y) + (a.z + a.w);
    s2 += (b.x + b.y) + (b.z + b.w);
    s3 += (c.x + c.y) + (c.z + c.w);
  }
  wave_reduce3(s1, s2, s3);
  __shared__ float l1[16], l2[16], l3[16];
  const int lane = tid & 63, wv = tid >> 6;
  if (lane == 0) { l1[wv] = s1; l2[wv] = s2; l3[wv] = s3; }
  __syncthreads();
  if (tid == 0) {
    float S1 = 0.f, S2 = 0.f, S3 = 0.f;
#pragma unroll
    for (int w = 0; w < 16; ++w) { S1 += l1[w]; S2 += l2[w]; S3 += l3[w]; }
    out[0] = MIU_ * fabsf(S1) + fabsf(S2) + S3 + ALPHA_ * (float)NTOT;
  }
}

extern "C" void kernel_launch(void* const* d_in, const int* in_sizes, int n_in,
                              void* d_out, int out_size, void* d_ws, size_t ws_size,
                              hipStream_t stream) {
  const float* pred  = (const float*)d_in[0];   // y_pred
  const float* truth = (const float*)d_in[1];   // y_true
  float* out      = (float*)d_out;
  float* partials = (float*)d_ws;               // 3*NBLK floats = 73.7 KB

  ace_main<<<NBLK, 512, 0, stream>>>(pred, truth, partials);
  ace_final<<<1, 1024, 0, stream>>>(partials, out);
}